// Round 6
// baseline (91.195 us; speedup 1.0000x reference)
//
#include <hip/hip_runtime.h>
#include <math.h>
#include <float.h>

#define N_RINGS  10
#define N_ANGLES 36
#define NP       (N_RINGS * N_ANGLES)   // 360 points per batch
#define PI_APPROX 3.1415926f

#define BLOCK  256        // 4 waves
#define WPB    4          // waves per block
#define CHUNK  512        // targets staged per block -> 32 chunks, 1024 blocks
#define NPAIR  (CHUNK / 2)
#define PPT    6          // point-slots per lane: 6*64 = 384 >= 360
#define RBLOCK 256        // reduce kernel block size

typedef float f2 __attribute__((ext_vector_type(2)));

// ---------------- kernel A: per-(batch, target-chunk) block --------------
// R5 skeleton (pk_fma + min3 inner loop, proven bit-exact). Final combine
// REPLACES the contended global atomicMin (R5: 368k device-scope RMWs onto
// 720 lines = ~512 serialized RMWs/line; every block's last wave drained
// vmcnt(0) on that before s_endpgm -> ~5-8 us tail, insensitive to inner
// optimizations) with 360 PLAIN coalesced stores to a private slice
// partial[b][cg][*]. Cross-chunk min moves to kernel B; visibility across
// the dispatch boundary is guaranteed by HSA kernel-end release /
// kernel-begin acquire. Block 0 zeroes kernel B's ticket counter, removing
// the hipMemsetAsync graph node entirely.
__global__ __launch_bounds__(BLOCK, 4) void chamfer_partial(
    const float* __restrict__ pred,    // B x N_RINGS
    const float* __restrict__ target,  // B x N x 3
    float* __restrict__ partial,       // B x chunks x NP
    unsigned int* __restrict__ counter,// 1 (ticket for kernel B)
    int N, int chunks)
{
    __shared__ float4 txy[NPAIR];         // {x0, x1, y0, y1}
    __shared__ float4 tzw[NPAIR];         // {z0, z1, w0, w1},  w = |t|^2
    __shared__ float  pm[WPB * NP];       // per-wave clamped partial mins
    __shared__ float  cs_c[N_ANGLES], cs_s[N_ANGLES];

    const int b   = blockIdx.x / chunks;
    const int cg  = blockIdx.x % chunks;
    const int n0  = cg * CHUNK;
    const int tid = threadIdx.x;
    const int cnt = min(CHUNK, N - n0);
    const int npairs = (cnt + 1) >> 1;

    if (blockIdx.x == 0 && tid == 0)
        *counter = 0u;                    // visible to kernel B at dispatch边界

    if (tid < N_ANGLES) {
        float angf = (float)(10 * tid) * (2.0f * PI_APPROX / 360.0f);
        double ang = (double)angf;
        cs_c[tid] = (float)cos(ang);
        cs_s[tid] = (float)sin(ang);
    }
    // stage target pairs: {x0,x1,y0,y1} and {z0,z1,w0,w1}
    for (int p = tid; p < npairs; p += BLOCK) {
        const int i0 = 2 * p;
        const int i1 = min(2 * p + 1, cnt - 1);   // dup last target if cnt odd
        const float* t0 = target + ((size_t)b * N + (size_t)(n0 + i0)) * 3;
        const float* t1 = target + ((size_t)b * N + (size_t)(n0 + i1)) * 3;
        float x0 = t0[0], y0 = t0[1], z0 = t0[2];
        float x1 = t1[0], y1 = t1[1], z1 = t1[2];
        float w0 = x0 * x0 + y0 * y0 + z0 * z0;
        float w1 = x1 * x1 + y1 * y1 + z1 * z1;
        txy[p] = make_float4(x0, x1, y0, y1);
        tzw[p] = make_float4(z0, z1, w0, w1);
    }
    __syncthreads();

    const int lane = tid & 63;
    const int w    = tid >> 6;

    // q = -2*p so inner pair = pk_fma(qz,Z, pk_fma(qy,Y, pk_fma(qx,X, W)))
    f2 qx2[PPT], qy2[PPT], qz2[PPT];
    float m[PPT], pp2[PPT];
    #pragma unroll
    for (int k = 0; k < PPT; ++k) {
        int s = lane + 64 * k;
        int j = s / N_ANGLES;
        int a = s - j * N_ANGLES;
        int jc = (j < N_RINGS) ? j : (N_RINGS - 1);   // clamp dummy slots
        float r  = pred[b * N_RINGS + jc];
        float px = -r * cs_c[a] + 0.04f;
        float py = 0.15f * (float)jc - 0.7f;
        float pz = r * cs_s[a];
        pp2[k] = px * px + py * py + pz * pz;
        float qxv = -2.0f * px, qyv = -2.0f * py, qzv = -2.0f * pz;
        qx2[k] = (f2){qxv, qxv};
        qy2[k] = (f2){qyv, qyv};
        qz2[k] = (f2){qzv, qzv};
        m[k]   = FLT_MAX;
    }

    // waves split the pair list; txy/tzw[k] are wave-uniform -> broadcast.
    // Per slot-pair: 3 v_pk_fma_f32 + 1 v_min3_f32 = 4 instr / 2 targets.
    #pragma unroll 4
    for (int k = w; k < npairs; k += WPB) {
        float4 A  = txy[k];
        float4 Bz = tzw[k];
        f2 X  = {A.x,  A.y };
        f2 Y  = {A.z,  A.w };
        f2 Z  = {Bz.x, Bz.y};
        f2 W2 = {Bz.z, Bz.w};
        #pragma unroll
        for (int i = 0; i < PPT; ++i) {
            f2 h = __builtin_elementwise_fma(qz2[i], Z, W2);
            h = __builtin_elementwise_fma(qy2[i], Y, h);
            h = __builtin_elementwise_fma(qx2[i], X, h);
            m[i] = fminf(fminf(m[i], h.x), h.y);   // -> v_min3_f32
        }
    }

    // finalize (add pp2, clamp) and publish per-wave partials
    #pragma unroll
    for (int k = 0; k < PPT; ++k) {
        int s = lane + 64 * k;
        if (s < NP) pm[w * NP + s] = fmaxf(pp2[k] + m[k], 0.0f);
    }
    __syncthreads();

    // cross-wave min, then 360 PLAIN coalesced stores (no atomics, no tail)
    float* dst = partial + ((size_t)b * chunks + cg) * NP;
    for (int p = tid; p < NP; p += BLOCK) {
        float v = fminf(fminf(pm[p], pm[NP + p]),
                        fminf(pm[2 * NP + p], pm[3 * NP + p]));
        dst[p] = v;
    }
}

// ---------------- kernel B: min over chunks + mean -----------------------
// One thread per (b, p): min over `chunks` coalesced strided loads
// (consecutive threads -> consecutive p -> fully coalesced per chunk).
// Per-block double sums published via agent-scope stores + ACQ_REL ticket;
// the last-arriving block sums nblocks doubles and writes the mean.
__global__ __launch_bounds__(RBLOCK) void reduce_minmean(
    const float* __restrict__ partial,   // B x chunks x NP
    double* __restrict__ sums,           // nblocks
    unsigned int* __restrict__ counter,  // zeroed by kernel A
    float* __restrict__ out,
    int chunks, int count, int nblocks)
{
    __shared__ double sm[RBLOCK / 64];
    const int tid = threadIdx.x;
    const int gid = blockIdx.x * RBLOCK + tid;
    const int lane = tid & 63;
    const int w    = tid >> 6;

    double s = 0.0;
    if (gid < count) {
        const int b = gid / NP;
        const int p = gid - b * NP;
        const float* base = partial + (size_t)b * chunks * NP + p;
        float mv = base[0];
        for (int c = 1; c < chunks; ++c)
            mv = fminf(mv, base[(size_t)c * NP]);
        s = (double)mv;
    }
    #pragma unroll
    for (int off = 32; off > 0; off >>= 1)
        s += __shfl_down(s, off, 64);
    if (lane == 0) sm[w] = s;
    __syncthreads();

    if (tid == 0) {
        double tot = 0.0;
        #pragma unroll
        for (int wv = 0; wv < RBLOCK / 64; ++wv) tot += sm[wv];
        __hip_atomic_store(&sums[blockIdx.x], tot, __ATOMIC_RELAXED,
                           __HIP_MEMORY_SCOPE_AGENT);
        unsigned int t = __hip_atomic_fetch_add(counter, 1u, __ATOMIC_ACQ_REL,
                                                __HIP_MEMORY_SCOPE_AGENT);
        if (t == (unsigned int)(nblocks - 1)) {   // last arrival
            double g = 0.0;
            for (int bk = 0; bk < nblocks; ++bk)
                g += __hip_atomic_load(&sums[bk], __ATOMIC_RELAXED,
                                       __HIP_MEMORY_SCOPE_AGENT);
            out[0] = (float)(g / (double)count);
        }
    }
}

extern "C" void kernel_launch(void* const* d_in, const int* in_sizes, int n_in,
                              void* d_out, int out_size, void* d_ws, size_t ws_size,
                              hipStream_t stream) {
    const float* pred   = (const float*)d_in[0];
    const float* target = (const float*)d_in[1];
    // d_in[2] (trans_feat) unused by the reference.

    const int B = in_sizes[0] / N_RINGS;
    const int N = in_sizes[1] / (3 * B);
    const int chunks  = (N + CHUNK - 1) / CHUNK;      // 32 for N=16384
    const int count   = B * NP;                       // 11520
    const int nblocks = (count + RBLOCK - 1) / RBLOCK;// 45

    // workspace layout: partial (B*chunks*NP f32), sums (nblocks f64), counter
    const size_t partial_elems = (size_t)B * chunks * NP;
    float*        partial = (float*)d_ws;
    double*       sums    = (double*)((char*)d_ws +
                            ((partial_elems * sizeof(float) + 7) & ~(size_t)7));
    unsigned int* counter = (unsigned int*)(sums + nblocks);
    float*        out     = (float*)d_out;

    hipLaunchKernelGGL(chamfer_partial, dim3(B * chunks), dim3(BLOCK), 0,
                       stream, pred, target, partial, counter, N, chunks);
    hipLaunchKernelGGL(reduce_minmean, dim3(nblocks), dim3(RBLOCK), 0, stream,
                       partial, sums, counter, out, chunks, count, nblocks);
}